// Round 7
// baseline (83.279 us; speedup 1.0000x reference)
//
#include <hip/hip_runtime.h>
#include <hip/hip_fp16.h>
#include <math.h>

#define SEQ 250
#define NCLS 12

// Butterfly add via DPP within 16-lane rows (zero DS-pipe ops).
// 0xB1=quad_perm(1,0,3,2) xor1; 0x4E=quad_perm(2,3,0,1) xor2;
// 0x141=row_half_mirror (lane^7, valid once quad-constant);
// 0x140=row_mirror (lane^15, valid once 8-group-constant).
template<int CTRL>
__device__ __forceinline__ float dpp_add(float v) {
    int t = __builtin_amdgcn_update_dpp(0, __float_as_int(v), CTRL, 0xF, 0xF, true);
    return v + __int_as_float(t);
}

// One block per batch element, 256 threads.
// LDS: s_bc 16000 + s_dlu 16000 + s_usz 16000 = 48,000 B -> 3 blocks/CU.
// NOTE (r4-r6 lesson): keeping sz in registers across the scan caused ~45 MB
// of scratch writes per dispatch (VGPR_Count pinned at 64 regardless of
// launch_bounds/waves_per_eu). sz therefore lives in LDS packed with u; the
// only cross-barrier register live range is szp across ONE barrier (the r3
// pattern, which showed zero scratch traffic).
__global__ __launch_bounds__(256)
void mamba_cls_kernel(
    const float* __restrict__ x,         // (B, 8, 250)
    const float* __restrict__ in_proj_w, // (32, 8)
    const float* __restrict__ conv_w,    // (16, 4)
    const float* __restrict__ conv_b,    // (16)
    const float* __restrict__ x_proj_w,  // (33, 16)
    const float* __restrict__ dt_proj_w, // (16, 1)
    const float* __restrict__ dt_proj_b, // (16)
    const float* __restrict__ A_log,     // (16, 16)
    const float* __restrict__ Dp,        // (16)
    const float* __restrict__ out_proj_w,// (8, 16)
    const float* __restrict__ fc_w,      // (12, 2000)
    const float* __restrict__ fc_b,      // (12)
    float* __restrict__ out)             // (B, 12)
{
    // s_bc : ph1 x_in (f32 view [t*16+d]); ph3+ {B,C} half2 [t*16+s];
    //        ph5b+ out2000 (f32 view [t*8+j])
    // s_dlu: ph3+ {dl,dl*u} half2 [t*16+s]; ph4+ y (f32 view, same word); ph6 partials
    // s_usz: ph0-1 staged x (f32 view, first 8000 B); ph2+ {u,sz} half2 [t*16+d]
    __shared__ __align__(16) __half2 s_bc [SEQ * 16];
    __shared__ __align__(16) __half2 s_dlu[SEQ * 16];
    __shared__ __align__(16) __half2 s_usz[SEQ * 16];

    const int b   = blockIdx.x;
    const int tid = threadIdx.x;
    float* s_f  = (float*)s_bc;
    float* s_y  = (float*)s_dlu;
    float* s_xf = (float*)s_usz;

    // ---- Phase 0: stage x coalesced (into the future {u,sz} region)
    {
        const float* __restrict__ xb = x + (size_t)b * (8 * SEQ);
        for (int i = tid; i < 8 * SEQ; i += 256) s_xf[i] = xb[i];
    }
    __syncthreads();

    // ---- Phase 1: x_in[t,d] -> s_f ; silu(z) packed fp16 -> 8 regs (dies in ph2)
    __half2 szp[8];
    {
        const int d  = tid & 15;
        const int t0 = tid >> 4;
        float w1[8], w2[8];
        #pragma unroll
        for (int m = 0; m < 8; ++m) {
            w1[m] = in_proj_w[d * 8 + m];
            w2[m] = in_proj_w[(16 + d) * 8 + m];
        }
        float sz_even = 0.f;
        #pragma unroll
        for (int i = 0; i < 16; ++i) {
            int t = t0 + i * 16;
            float sz = 0.f;
            if (t < SEQ) {
                float acc = 0.f, z = 0.f;
                #pragma unroll
                for (int m = 0; m < 8; ++m) {
                    float xv = s_xf[m * SEQ + t];
                    acc = fmaf(w1[m], xv, acc);
                    z   = fmaf(w2[m], xv, z);
                }
                s_f[t * 16 + d] = acc;
                sz = z / (1.f + __expf(-z));
            }
            if (i & 1) szp[i >> 1] = __floats2half2_rn(sz_even, sz);
            else       sz_even = sz;
        }
    }
    __syncthreads();

    // ---- Phase 2: causal conv(k=4)+SiLU -> {u, sz} half2 (overwrites dead x)
    {
        const int d  = tid & 15;
        const int t0 = tid >> 4;
        float cw[4];
        #pragma unroll
        for (int k = 0; k < 4; ++k) cw[k] = conv_w[d * 4 + k];
        const float cb = conv_b[d];
        #pragma unroll
        for (int i = 0; i < 16; ++i) {
            int t = t0 + i * 16;
            if (t < SEQ) {
                float acc = cb;
                #pragma unroll
                for (int k = 0; k < 4; ++k) {
                    int tt = t + k - 3;
                    if (tt >= 0) acc = fmaf(cw[k], s_f[tt * 16 + d], acc);
                }
                float sg = 1.f / (1.f + __expf(-acc));
                float2 szv = __half22float2(szp[i >> 1]);
                float sz = (i & 1) ? szv.y : szv.x;
                s_usz[t * 16 + d] = __floats2half2_rn(acc * sg, sz);
            }
        }
    }
    __syncthreads();

    // ---- Phase 3: {B,C} -> s_bc ; {dl, dl*u} -> s_dlu (dt redundant per s-lane)
    {
        const int s = tid & 15;
        __half2 wb2[8], wc2[8], wd2[8];
        #pragma unroll
        for (int k = 0; k < 8; ++k) {
            wb2[k] = __floats2half2_rn(x_proj_w[(1 + s) * 16 + 2 * k],
                                       x_proj_w[(1 + s) * 16 + 2 * k + 1]);
            wc2[k] = __floats2half2_rn(x_proj_w[(17 + s) * 16 + 2 * k],
                                       x_proj_w[(17 + s) * 16 + 2 * k + 1]);
            wd2[k] = __floats2half2_rn(x_proj_w[2 * k], x_proj_w[2 * k + 1]);
        }
        const float dws = dt_proj_w[s];
        const float dbs = dt_proj_b[s];
        const __half2 zero2 = __float2half2_rn(0.f);
        for (int t = tid >> 4; t < SEQ; t += 16) {
            const __half2* up = s_usz + t * 16;   // {u, sz} per d
            __half2 ab = zero2, ac = zero2, ad = zero2;
            #pragma unroll
            for (int k = 0; k < 8; ++k) {
                __half2 uv = __lows2half2(up[2 * k], up[2 * k + 1]); // {u2k, u2k+1}
                ab = __hfma2(uv, wb2[k], ab);
                ac = __hfma2(uv, wc2[k], ac);
                ad = __hfma2(uv, wd2[k], ad);
            }
            float abf = __half2float(__low2half(ab)) + __half2float(__high2half(ab));
            float acf = __half2float(__low2half(ac)) + __half2float(__high2half(ac));
            float adf = __half2float(__low2half(ad)) + __half2float(__high2half(ad));
            s_bc[t * 16 + s] = __floats2half2_rn(abf, acf);
            float v  = fmaf(adf, dws, dbs);
            float dl = (v > 20.f) ? v : __logf(1.f + __expf(v));
            float uf = __half2float(__low2half(s_usz[t * 16 + s]));
            s_dlu[t * 16 + s] = __floats2half2_rn(dl, dl * uf);
        }
    }
    __syncthreads();

    // ---- Phase 4: scan. thread = (d = tid>>4, s = tid&15); 2 LDS reads per t.
    {
        const int d = tid >> 4;
        const int s = tid & 15;
        const float A2 = -__expf(A_log[d * 16 + s]) * 1.4426950408889634f;
        float h = 0.f;
        #pragma unroll 5
        for (int t = 0; t < SEQ; ++t) {
            float2 dlu = __half22float2(s_dlu[t * 16 + d]);  // {dl, dl*u} bcast over s
            float2 bc  = __half22float2(s_bc [t * 16 + s]);  // {B, C}    bcast over d
            float dA = exp2f(dlu.x * A2);
            h = fmaf(dA, h, dlu.y * bc.x);
            float r = h * bc.y;
            r = dpp_add<0xB1>(r);
            r = dpp_add<0x4E>(r);
            r = dpp_add<0x141>(r);
            r = dpp_add<0x140>(r);
            if (s == 0) s_y[t * 16 + d] = r;   // y_raw over the dead {dl,dlu} word
        }
    }
    __syncthreads();

    // ---- Phase 5: y = (y_raw + u*D) * silu(z)   ({u,sz} one LDS load)
    {
        const int d  = tid & 15;
        const int t0 = tid >> 4;
        const float Dd = Dp[d];
        #pragma unroll
        for (int i = 0; i < 16; ++i) {
            int t = t0 + i * 16;
            if (t < SEQ) {
                float2 usz = __half22float2(s_usz[t * 16 + d]);
                s_y[t * 16 + d] = fmaf(usz.x, Dd, s_y[t * 16 + d]) * usz.y;
            }
        }
    }
    __syncthreads();

    // ---- Phase 5b: out2000[t*8+j] = sum_d y[t,d]*out_proj_w[j,d] (into s_f)
    {
        const int j = tid & 7;
        float w[16];
        #pragma unroll
        for (int d2 = 0; d2 < 16; ++d2) w[d2] = out_proj_w[j * 16 + d2];
        for (int t = tid >> 3; t < SEQ; t += 32) {
            float a = 0.f;
            #pragma unroll
            for (int d2 = 0; d2 < 16; ++d2) a = fmaf(w[d2], s_y[t * 16 + d2], a);
            s_f[t * 8 + j] = a;
        }
    }
    __syncthreads();

    // ---- Phase 6: logits[c] = out2000 . fc_w[c,:] + fc_b[c]  (float4 loads)
    {
        float p[NCLS];
        #pragma unroll
        for (int c = 0; c < NCLS; ++c) p[c] = 0.f;
        const float4* fw4 = (const float4*)fc_w;
        const float4* sf4 = (const float4*)s_f;
        for (int q = tid; q < 500; q += 256) {
            float4 f = sf4[q];
            #pragma unroll
            for (int c = 0; c < NCLS; ++c) {
                float4 wv = fw4[c * 500 + q];
                p[c] += f.x * wv.x + f.y * wv.y + f.z * wv.z + f.w * wv.w;
            }
        }
        #pragma unroll
        for (int c = 0; c < NCLS; ++c) {
            float v = p[c];
            v = dpp_add<0xB1>(v);
            v = dpp_add<0x4E>(v);
            v = dpp_add<0x141>(v);
            v = dpp_add<0x140>(v);
            v += __shfl_xor(v, 16);
            v += __shfl_xor(v, 32);
            p[c] = v;
        }
        const int wave = tid >> 6;
        const int lane = tid & 63;
        if (lane == 0) {
            #pragma unroll
            for (int c = 0; c < NCLS; ++c) s_y[wave * NCLS + c] = p[c];
        }
        __syncthreads();
        if (tid < NCLS) {
            float v = s_y[tid] + s_y[NCLS + tid] + s_y[2 * NCLS + tid] +
                      s_y[3 * NCLS + tid] + fc_b[tid];
            out[(size_t)b * NCLS + tid] = v;
        }
    }
}

extern "C" void kernel_launch(void* const* d_in, const int* in_sizes, int n_in,
                              void* d_out, int out_size, void* d_ws, size_t ws_size,
                              hipStream_t stream) {
    const float* x          = (const float*)d_in[0];
    const float* in_proj_w  = (const float*)d_in[1];
    const float* conv_w     = (const float*)d_in[2];
    const float* conv_b     = (const float*)d_in[3];
    const float* x_proj_w   = (const float*)d_in[4];
    const float* dt_proj_w  = (const float*)d_in[5];
    const float* dt_proj_b  = (const float*)d_in[6];
    const float* A_log      = (const float*)d_in[7];
    const float* Dp         = (const float*)d_in[8];
    const float* out_proj_w = (const float*)d_in[9];
    const float* fc_w       = (const float*)d_in[10];
    const float* fc_b       = (const float*)d_in[11];
    float* out = (float*)d_out;

    const int batch = in_sizes[0] / (8 * SEQ);  // 1024
    mamba_cls_kernel<<<batch, 256, 0, stream>>>(
        x, in_proj_w, conv_w, conv_b, x_proj_w, dt_proj_w, dt_proj_b,
        A_log, Dp, out_proj_w, fc_w, fc_b, out);
}

// Round 8
// 71.853 us; speedup vs baseline: 1.1590x; 1.1590x over previous
//
#include <hip/hip_runtime.h>
#include <hip/hip_fp16.h>
#include <math.h>

#define SEQ 250
#define NCLS 12

// Butterfly add via DPP within 16-lane rows (zero DS-pipe ops).
// 0xB1=quad_perm(1,0,3,2) xor1; 0x4E=quad_perm(2,3,0,1) xor2;
// 0x141=row_half_mirror (valid once quad-constant);
// 0x140=row_mirror (valid once 8-group-constant).
template<int CTRL>
__device__ __forceinline__ float dpp_add(float v) {
    int t = __builtin_amdgcn_update_dpp(0, __float_as_int(v), CTRL, 0xF, 0xF, true);
    return v + __int_as_float(t);
}

__device__ __forceinline__ __half2 f_as_h2(float f) {
    union { float f; __half2 h; } u; u.f = f; return u.h;
}

// One block per batch element, 256 threads.
// LDS: s_bc 16000 + s_dlu 16000 + s_sz 8000 = 40,000 B -> 4 blocks/CU (16 waves).
// r4-r6 lesson: any register live range spanning the scan gets spilled to
// scratch (~45 MB/dispatch). All cross-phase state lives in LDS; sz is written
// in ph1 directly (no cross-barrier regs). Layouts are d-major [chan*250+t] so
// the scan reads {dl,u} and {B,C} as one b64 per TWO timesteps.
__global__ __launch_bounds__(256)
void mamba_cls_kernel(
    const float* __restrict__ x,         // (B, 8, 250)
    const float* __restrict__ in_proj_w, // (32, 8)
    const float* __restrict__ conv_w,    // (16, 4)
    const float* __restrict__ conv_b,    // (16)
    const float* __restrict__ x_proj_w,  // (33, 16)
    const float* __restrict__ dt_proj_w, // (16, 1)
    const float* __restrict__ dt_proj_b, // (16)
    const float* __restrict__ A_log,     // (16, 16)
    const float* __restrict__ Dp,        // (16)
    const float* __restrict__ out_proj_w,// (8, 16)
    const float* __restrict__ fc_w,      // (12, 2000)
    const float* __restrict__ fc_b,      // (12)
    float* __restrict__ out)             // (B, 12)
{
    // s_bc : ph1-2 x_in (f32 view [d*250+t]); ph3+ {B,C} half2 [s*250+t];
    //        ph5b+ out2000 (f32 view [t*8+j])
    // s_dlu: ph0-1 staged x (f32 view, first 8000B); ph2+ {dl,u} half2 [d*250+t]
    //        (u in .y from ph2, dl in .x from ph3); ph4+ y (f32, same word);
    //        ph6 reduce partials
    // s_sz : silu(z) fp16 [d*250+t]
    __shared__ __align__(16) __half2 s_bc [16 * SEQ];
    __shared__ __align__(16) __half2 s_dlu[16 * SEQ];
    __shared__ __align__(16) __half  s_sz [16 * SEQ];

    const int b   = blockIdx.x;
    const int tid = threadIdx.x;
    float* s_f  = (float*)s_bc;   // x_in / out2000 views
    float* s_yf = (float*)s_dlu;  // y view
    float* s_xf = (float*)s_dlu;  // x staging view

    // ---- Phase 0: stage x coalesced (into the future {dl,u} region)
    {
        const float* __restrict__ xb = x + (size_t)b * (8 * SEQ);
        for (int i = tid; i < 8 * SEQ; i += 256) s_xf[i] = xb[i];
    }
    __syncthreads();

    // ---- Phase 1: x_in[d*250+t] -> s_f ; silu(z) -> s_sz (no reg carry)
    {
        const int d  = tid & 15;
        const int t0 = tid >> 4;
        float w1[8], w2[8];
        #pragma unroll
        for (int m = 0; m < 8; ++m) {
            w1[m] = in_proj_w[d * 8 + m];
            w2[m] = in_proj_w[(16 + d) * 8 + m];
        }
        #pragma unroll
        for (int i = 0; i < 16; ++i) {
            int t = t0 + i * 16;
            if (t < SEQ) {
                float acc = 0.f, z = 0.f;
                #pragma unroll
                for (int m = 0; m < 8; ++m) {
                    float xv = s_xf[m * SEQ + t];
                    acc = fmaf(w1[m], xv, acc);
                    z   = fmaf(w2[m], xv, z);
                }
                s_f[d * SEQ + t] = acc;
                s_sz[d * SEQ + t] = __float2half(z / (1.f + __expf(-z)));
            }
        }
    }
    __syncthreads();

    // ---- Phase 2: causal conv(k=4)+SiLU -> u into s_dlu[d*250+t].y
    //      (b16 writes over the dead x staging)
    {
        const int d  = tid & 15;
        const int t0 = tid >> 4;
        float cw[4];
        #pragma unroll
        for (int k = 0; k < 4; ++k) cw[k] = conv_w[d * 4 + k];
        const float cb = conv_b[d];
        #pragma unroll
        for (int i = 0; i < 16; ++i) {
            int t = t0 + i * 16;
            if (t < SEQ) {
                float acc = cb;
                #pragma unroll
                for (int k = 0; k < 4; ++k) {
                    int tt = t + k - 3;
                    if (tt >= 0) acc = fmaf(cw[k], s_f[d * SEQ + tt], acc);
                }
                float sg = 1.f / (1.f + __expf(-acc));
                s_dlu[d * SEQ + t].y = __float2half(acc * sg);
            }
        }
    }
    __syncthreads();

    // ---- Phase 3: {B,C} -> s_bc[s*250+t] ; dl -> s_dlu[s*250+t].x
    //      (dt computed redundantly per s-lane; u gathered via .y halves)
    {
        const int s = tid & 15;
        __half2 wb2[8], wc2[8], wd2[8];
        #pragma unroll
        for (int k = 0; k < 8; ++k) {
            wb2[k] = __floats2half2_rn(x_proj_w[(1 + s) * 16 + 2 * k],
                                       x_proj_w[(1 + s) * 16 + 2 * k + 1]);
            wc2[k] = __floats2half2_rn(x_proj_w[(17 + s) * 16 + 2 * k],
                                       x_proj_w[(17 + s) * 16 + 2 * k + 1]);
            wd2[k] = __floats2half2_rn(x_proj_w[2 * k], x_proj_w[2 * k + 1]);
        }
        const float dws = dt_proj_w[s];
        const float dbs = dt_proj_b[s];
        const __half2 zero2 = __float2half2_rn(0.f);
        for (int t = tid >> 4; t < SEQ; t += 16) {
            __half2 ab = zero2, ac = zero2, ad = zero2;
            #pragma unroll
            for (int k = 0; k < 8; ++k) {
                __half2 uv = __halves2half2(
                    __high2half(s_dlu[(2 * k) * SEQ + t]),
                    __high2half(s_dlu[(2 * k + 1) * SEQ + t]));
                ab = __hfma2(uv, wb2[k], ab);
                ac = __hfma2(uv, wc2[k], ac);
                ad = __hfma2(uv, wd2[k], ad);
            }
            float abf = __half2float(__low2half(ab)) + __half2float(__high2half(ab));
            float acf = __half2float(__low2half(ac)) + __half2float(__high2half(ac));
            float adf = __half2float(__low2half(ad)) + __half2float(__high2half(ad));
            s_bc[s * SEQ + t] = __floats2half2_rn(abf, acf);
            float v  = fmaf(adf, dws, dbs);
            float dl = (v > 20.f) ? v : __logf(1.f + __expf(v));
            s_dlu[s * SEQ + t].x = __float2half(dl);
        }
    }
    __syncthreads();

    // ---- Phase 4: scan. thread = (d = tid>>4, s = tid&15).
    // One b64 {dl,u} + one b64 {B,C} + one b32 sz per TWO timesteps.
    // y = (sum_s h*C + u*D) * sz written (f32) over the consumed {dl,u} word;
    // only this wave's d-rows are touched -> race-free.
    {
        const int d = tid >> 4;
        const int s = tid & 15;
        const float A2 = -__expf(A_log[d * 16 + s]) * 1.4426950408889634f;
        const float Dd = Dp[d];
        const __half2* __restrict__ dlu_p = s_dlu + d * SEQ;
        const __half2* __restrict__ bc_p  = s_bc  + s * SEQ;
        const __half*  __restrict__ sz_p  = s_sz  + d * SEQ;
        float* __restrict__ y_p = s_yf + d * SEQ;
        float h = 0.f;
        #pragma unroll 5
        for (int t = 0; t < SEQ; t += 2) {
            float2 duv = *reinterpret_cast<const float2*>(dlu_p + t);
            float2 bcv = *reinterpret_cast<const float2*>(bc_p + t);
            float2 szf = __half22float2(*reinterpret_cast<const __half2*>(sz_p + t));

            float2 du0 = __half22float2(f_as_h2(duv.x));   // {dl, u} @ t
            float2 bc0 = __half22float2(f_as_h2(bcv.x));   // {B, C} @ t
            float dA0 = exp2f(du0.x * A2);
            h = fmaf(dA0, h, du0.x * du0.y * bc0.x);
            float r0 = h * bc0.y;
            r0 = dpp_add<0xB1>(r0);
            r0 = dpp_add<0x4E>(r0);
            r0 = dpp_add<0x141>(r0);
            r0 = dpp_add<0x140>(r0);
            if (s == 0) y_p[t] = fmaf(du0.y, Dd, r0) * szf.x;

            float2 du1 = __half22float2(f_as_h2(duv.y));   // {dl, u} @ t+1
            float2 bc1 = __half22float2(f_as_h2(bcv.y));   // {B, C} @ t+1
            float dA1 = exp2f(du1.x * A2);
            h = fmaf(dA1, h, du1.x * du1.y * bc1.x);
            float r1 = h * bc1.y;
            r1 = dpp_add<0xB1>(r1);
            r1 = dpp_add<0x4E>(r1);
            r1 = dpp_add<0x141>(r1);
            r1 = dpp_add<0x140>(r1);
            if (s == 0) y_p[t + 1] = fmaf(du1.y, Dd, r1) * szf.y;
        }
    }
    __syncthreads();

    // ---- Phase 5b: out2000[t*8+j] = sum_d y[d,t]*out_proj_w[j,d]
    //      (into s_f over the dead {B,C})
    {
        const int j = tid & 7;
        float w[16];
        #pragma unroll
        for (int d2 = 0; d2 < 16; ++d2) w[d2] = out_proj_w[j * 16 + d2];
        for (int t = tid >> 3; t < SEQ; t += 32) {
            float a = 0.f;
            #pragma unroll
            for (int d2 = 0; d2 < 16; ++d2) a = fmaf(w[d2], s_yf[d2 * SEQ + t], a);
            s_f[t * 8 + j] = a;
        }
    }
    __syncthreads();

    // ---- Phase 6: logits[c] = out2000 . fc_w[c,:] + fc_b[c]  (float4 loads)
    {
        float p[NCLS];
        #pragma unroll
        for (int c = 0; c < NCLS; ++c) p[c] = 0.f;
        const float4* fw4 = (const float4*)fc_w;
        const float4* sf4 = (const float4*)s_f;
        for (int q = tid; q < 500; q += 256) {
            float4 f = sf4[q];
            #pragma unroll
            for (int c = 0; c < NCLS; ++c) {
                float4 wv = fw4[c * 500 + q];
                p[c] += f.x * wv.x + f.y * wv.y + f.z * wv.z + f.w * wv.w;
            }
        }
        #pragma unroll
        for (int c = 0; c < NCLS; ++c) {
            float v = p[c];
            v = dpp_add<0xB1>(v);
            v = dpp_add<0x4E>(v);
            v = dpp_add<0x141>(v);
            v = dpp_add<0x140>(v);
            v += __shfl_xor(v, 16);
            v += __shfl_xor(v, 32);
            p[c] = v;
        }
        const int wave = tid >> 6;
        const int lane = tid & 63;
        __syncthreads();   // y consumed; reuse s_yf as reduce buffer
        if (lane == 0) {
            #pragma unroll
            for (int c = 0; c < NCLS; ++c) s_yf[wave * NCLS + c] = p[c];
        }
        __syncthreads();
        if (tid < NCLS) {
            float v = s_yf[tid] + s_yf[NCLS + tid] + s_yf[2 * NCLS + tid] +
                      s_yf[3 * NCLS + tid] + fc_b[tid];
            out[(size_t)b * NCLS + tid] = v;
        }
    }
}

extern "C" void kernel_launch(void* const* d_in, const int* in_sizes, int n_in,
                              void* d_out, int out_size, void* d_ws, size_t ws_size,
                              hipStream_t stream) {
    const float* x          = (const float*)d_in[0];
    const float* in_proj_w  = (const float*)d_in[1];
    const float* conv_w     = (const float*)d_in[2];
    const float* conv_b     = (const float*)d_in[3];
    const float* x_proj_w   = (const float*)d_in[4];
    const float* dt_proj_w  = (const float*)d_in[5];
    const float* dt_proj_b  = (const float*)d_in[6];
    const float* A_log      = (const float*)d_in[7];
    const float* Dp         = (const float*)d_in[8];
    const float* out_proj_w = (const float*)d_in[9];
    const float* fc_w       = (const float*)d_in[10];
    const float* fc_b       = (const float*)d_in[11];
    float* out = (float*)d_out;

    const int batch = in_sizes[0] / (8 * SEQ);  // 1024
    mamba_cls_kernel<<<batch, 256, 0, stream>>>(
        x, in_proj_w, conv_w, conv_b, x_proj_w, dt_proj_w, dt_proj_b,
        A_log, Dp, out_proj_w, fc_w, fc_b, out);
}

// Round 10
// 63.325 us; speedup vs baseline: 1.3151x; 1.1347x over previous
//
#include <hip/hip_runtime.h>
#include <hip/hip_fp16.h>
#include <math.h>

#define SEQ 250
#define NCLS 12

// Butterfly add via DPP (zero DS-pipe ops).
// 0xB1=quad_perm(1,0,3,2) xor1; 0x4E=quad_perm(2,3,0,1) xor2;
// 0x141=row_half_mirror (lane^7 within 8; valid once quad-constant);
// 0x140=row_mirror (lane^15 within 16; valid once 8-group-constant).
template<int CTRL>
__device__ __forceinline__ float dpp_add(float v) {
    int t = __builtin_amdgcn_update_dpp(0, __float_as_int(v), CTRL, 0xF, 0xF, true);
    return v + __int_as_float(t);
}

__device__ __forceinline__ __half2 f_as_h2(float f) {
    union { float f; __half2 h; } u; u.f = f; return u.h;
}

// 512 threads, TWO batch elements per block.
// LDS: 2 x (s_bc 16000 + s_dlu 16000 + s_sz 8000) = 80,000 B -> 2 blocks/CU
// = 16 waves/CU.
// r4-r6 lesson: no register live ranges across the scan (spill -> 45 MB HBM
// scratch). All cross-phase state in LDS.
// r9 lesson: phase 0 stages BOTH problems' x contiguously from s_dlu[0]
// (p=1 at byte offset 8000, NOT at s_dlu[1]) — phase 1 must read
// (float*)s_dlu[0] + p*2000, not (float*)s_dlu[p].
// Scan is s-folded x2: each problem runs on 2 waves (128 thr = 16d x 8 lanes,
// each lane owns s2 and s2+8). Waves 0-1 -> problem 0, waves 2-3 -> problem 1;
// waves 4-7 park at the barrier (no issue slots). Shared-across-s work
// ({dl,u} read/cvt, dl*u, sz, y-write) amortizes over 2 states; reduce is
// 3 DPP stages instead of 4.
__global__ __launch_bounds__(512)
void mamba_cls_kernel(
    const float* __restrict__ x,         // (B, 8, 250)
    const float* __restrict__ in_proj_w, // (32, 8)
    const float* __restrict__ conv_w,    // (16, 4)
    const float* __restrict__ conv_b,    // (16)
    const float* __restrict__ x_proj_w,  // (33, 16)
    const float* __restrict__ dt_proj_w, // (16, 1)
    const float* __restrict__ dt_proj_b, // (16)
    const float* __restrict__ A_log,     // (16, 16)
    const float* __restrict__ Dp,        // (16)
    const float* __restrict__ out_proj_w,// (8, 16)
    const float* __restrict__ fc_w,      // (12, 2000)
    const float* __restrict__ fc_b,      // (12)
    float* __restrict__ out)             // (B, 12)
{
    // Per problem p:
    // s_bc [p]: ph1-2 x_in (f32 view [d*250+t]); ph3+ {B,C} half2 [s*250+t];
    //           ph5b+ out2000 (f32 view [t*8+j])
    // s_dlu   : ph0-1 staged x of BOTH problems (f32 view, 16000 B from
    //           s_dlu[0]); ph2+ {dl,u} half2 [d*250+t] per problem
    //           (u=.y from ph2, dl=.x from ph3); ph4+ y (f32, same word);
    //           ph6 reduce partials
    // s_sz [p]: silu(z) fp16 [d*250+t]
    __shared__ __align__(16) __half2 s_bc [2][16 * SEQ];
    __shared__ __align__(16) __half2 s_dlu[2][16 * SEQ];
    __shared__ __align__(16) __half  s_sz [2][16 * SEQ];

    const int tid  = threadIdx.x;
    const int p    = tid >> 8;        // problem 0/1 (phases)
    const int tid8 = tid & 255;       // per-problem thread id (phases)
    const int b0   = blockIdx.x * 2;  // first batch element of this block

    // ---- Phase 0: stage x for BOTH problems coalesced (x rows are contiguous)
    {
        float* s_xf = (float*)s_dlu[0];  // 4000 floats = 16000 B, fills s_dlu[0..1] halves
        const float* __restrict__ xb = x + (size_t)b0 * (8 * SEQ);
        for (int i = tid; i < 2 * 8 * SEQ; i += 512) s_xf[i] = xb[i];
    }
    __syncthreads();

    // ---- Phase 1: x_in[d*250+t] -> s_f ; silu(z) -> s_sz
    {
        float* s_f  = (float*)s_bc[p];
        const float* s_xf = (const float*)s_dlu[0] + p * (8 * SEQ);  // r9 bugfix
        const int d  = tid8 & 15;
        const int t0 = tid8 >> 4;
        float w1[8], w2[8];
        #pragma unroll
        for (int m = 0; m < 8; ++m) {
            w1[m] = in_proj_w[d * 8 + m];
            w2[m] = in_proj_w[(16 + d) * 8 + m];
        }
        #pragma unroll
        for (int i = 0; i < 16; ++i) {
            int t = t0 + i * 16;
            if (t < SEQ) {
                float acc = 0.f, z = 0.f;
                #pragma unroll
                for (int m = 0; m < 8; ++m) {
                    float xv = s_xf[m * SEQ + t];
                    acc = fmaf(w1[m], xv, acc);
                    z   = fmaf(w2[m], xv, z);
                }
                s_f[d * SEQ + t] = acc;
                s_sz[p][d * SEQ + t] = __float2half(z / (1.f + __expf(-z)));
            }
        }
    }
    __syncthreads();

    // ---- Phase 2: causal conv(k=4)+SiLU -> u into s_dlu[p][d*250+t].y
    //      (b16 writes over the dead x staging)
    {
        const float* s_f = (const float*)s_bc[p];
        const int d  = tid8 & 15;
        const int t0 = tid8 >> 4;
        float cw[4];
        #pragma unroll
        for (int k = 0; k < 4; ++k) cw[k] = conv_w[d * 4 + k];
        const float cb = conv_b[d];
        #pragma unroll
        for (int i = 0; i < 16; ++i) {
            int t = t0 + i * 16;
            if (t < SEQ) {
                float acc = cb;
                #pragma unroll
                for (int k = 0; k < 4; ++k) {
                    int tt = t + k - 3;
                    if (tt >= 0) acc = fmaf(cw[k], s_f[d * SEQ + tt], acc);
                }
                float sg = 1.f / (1.f + __expf(-acc));
                s_dlu[p][d * SEQ + t].y = __float2half(acc * sg);
            }
        }
    }
    __syncthreads();

    // ---- Phase 3: {B,C} -> s_bc[p][s*250+t] ; dl -> s_dlu[p][s*250+t].x
    {
        const int s = tid8 & 15;
        __half2 wb2[8], wc2[8], wd2[8];
        #pragma unroll
        for (int k = 0; k < 8; ++k) {
            wb2[k] = __floats2half2_rn(x_proj_w[(1 + s) * 16 + 2 * k],
                                       x_proj_w[(1 + s) * 16 + 2 * k + 1]);
            wc2[k] = __floats2half2_rn(x_proj_w[(17 + s) * 16 + 2 * k],
                                       x_proj_w[(17 + s) * 16 + 2 * k + 1]);
            wd2[k] = __floats2half2_rn(x_proj_w[2 * k], x_proj_w[2 * k + 1]);
        }
        const float dws = dt_proj_w[s];
        const float dbs = dt_proj_b[s];
        const __half2 zero2 = __float2half2_rn(0.f);
        for (int t = tid8 >> 4; t < SEQ; t += 16) {
            __half2 ab = zero2, ac = zero2, ad = zero2;
            #pragma unroll
            for (int k = 0; k < 8; ++k) {
                __half2 uv = __halves2half2(
                    __high2half(s_dlu[p][(2 * k) * SEQ + t]),
                    __high2half(s_dlu[p][(2 * k + 1) * SEQ + t]));
                ab = __hfma2(uv, wb2[k], ab);
                ac = __hfma2(uv, wc2[k], ac);
                ad = __hfma2(uv, wd2[k], ad);
            }
            float abf = __half2float(__low2half(ab)) + __half2float(__high2half(ab));
            float acf = __half2float(__low2half(ac)) + __half2float(__high2half(ac));
            float adf = __half2float(__low2half(ad)) + __half2float(__high2half(ad));
            s_bc[p][s * SEQ + t] = __floats2half2_rn(abf, acf);
            float v  = fmaf(adf, dws, dbs);
            float dl = (v > 20.f) ? v : __logf(1.f + __expf(v));
            s_dlu[p][s * SEQ + t].x = __float2half(dl);
        }
    }
    __syncthreads();

    // ---- Phase 4: scan, s-folded x2. Active: tid<256 (waves 0-3).
    // wave 0-1 -> problem 0, wave 2-3 -> problem 1; per problem 128 threads:
    // d = (tid&127)>>3, s2 = tid&7, states s2 and s2+8.
    if (tid < 256) {
        const int sp   = tid >> 7;          // scan problem
        const int i7   = tid & 127;
        const int d    = i7 >> 3;
        const int s2   = i7 & 7;
        const float A2a = -__expf(A_log[d * 16 + s2])     * 1.4426950408889634f;
        const float A2b = -__expf(A_log[d * 16 + s2 + 8]) * 1.4426950408889634f;
        const float Dd  = Dp[d];
        const __half2* __restrict__ dlu_p = s_dlu[sp] + d * SEQ;
        const __half2* __restrict__ bca_p = s_bc [sp] + s2 * SEQ;
        const __half2* __restrict__ bcb_p = s_bc [sp] + (s2 + 8) * SEQ;
        const __half*  __restrict__ sz_p  = (const __half*)s_sz[sp] + d * SEQ;
        float* __restrict__ y_p = (float*)s_dlu[sp] + d * SEQ;
        float ha = 0.f, hb = 0.f;
        #pragma unroll 5
        for (int t = 0; t < SEQ; t += 2) {
            float2 duv  = *reinterpret_cast<const float2*>(dlu_p + t);
            float2 bcav = *reinterpret_cast<const float2*>(bca_p + t);
            float2 bcbv = *reinterpret_cast<const float2*>(bcb_p + t);
            float2 szf  = __half22float2(*reinterpret_cast<const __half2*>(sz_p + t));

            {   // t
                float2 du  = __half22float2(f_as_h2(duv.x));   // {dl, u}
                float2 bca = __half22float2(f_as_h2(bcav.x));  // {B, C} @ s2
                float2 bcb = __half22float2(f_as_h2(bcbv.x));  // {B, C} @ s2+8
                float dlu = du.x * du.y;
                ha = fmaf(exp2f(du.x * A2a), ha, dlu * bca.x);
                hb = fmaf(exp2f(du.x * A2b), hb, dlu * bcb.x);
                float r = fmaf(hb, bcb.y, ha * bca.y);
                r = dpp_add<0xB1>(r);
                r = dpp_add<0x4E>(r);
                r = dpp_add<0x141>(r);
                if (s2 == 0) y_p[t] = fmaf(du.y, Dd, r) * szf.x;
            }
            {   // t+1
                float2 du  = __half22float2(f_as_h2(duv.y));
                float2 bca = __half22float2(f_as_h2(bcav.y));
                float2 bcb = __half22float2(f_as_h2(bcbv.y));
                float dlu = du.x * du.y;
                ha = fmaf(exp2f(du.x * A2a), ha, dlu * bca.x);
                hb = fmaf(exp2f(du.x * A2b), hb, dlu * bcb.x);
                float r = fmaf(hb, bcb.y, ha * bca.y);
                r = dpp_add<0xB1>(r);
                r = dpp_add<0x4E>(r);
                r = dpp_add<0x141>(r);
                if (s2 == 0) y_p[t + 1] = fmaf(du.y, Dd, r) * szf.y;
            }
        }
    }
    __syncthreads();

    // ---- Phase 5b: out2000[t*8+j] = sum_d y[d,t]*out_proj_w[j,d]
    //      (into s_f over the dead {B,C})
    {
        float* s_f  = (float*)s_bc[p];
        const float* s_yf = (const float*)s_dlu[p];
        const int j = tid8 & 7;
        float w[16];
        #pragma unroll
        for (int d2 = 0; d2 < 16; ++d2) w[d2] = out_proj_w[j * 16 + d2];
        for (int t = tid8 >> 3; t < SEQ; t += 32) {
            float a = 0.f;
            #pragma unroll
            for (int d2 = 0; d2 < 16; ++d2) a = fmaf(w[d2], s_yf[d2 * SEQ + t], a);
            s_f[t * 8 + j] = a;
        }
    }
    __syncthreads();

    // ---- Phase 6: logits[c] = out2000 . fc_w[c,:] + fc_b[c]  (float4 loads)
    {
        float* s_yf = (float*)s_dlu[p];
        float p_[NCLS];
        #pragma unroll
        for (int c = 0; c < NCLS; ++c) p_[c] = 0.f;
        const float4* fw4 = (const float4*)fc_w;
        const float4* sf4 = (const float4*)s_bc[p];
        for (int q = tid8; q < 500; q += 256) {
            float4 f = sf4[q];
            #pragma unroll
            for (int c = 0; c < NCLS; ++c) {
                float4 wv = fw4[c * 500 + q];
                p_[c] += f.x * wv.x + f.y * wv.y + f.z * wv.z + f.w * wv.w;
            }
        }
        #pragma unroll
        for (int c = 0; c < NCLS; ++c) {
            float v = p_[c];
            v = dpp_add<0xB1>(v);
            v = dpp_add<0x4E>(v);
            v = dpp_add<0x141>(v);
            v = dpp_add<0x140>(v);
            v += __shfl_xor(v, 16);
            v += __shfl_xor(v, 32);
            p_[c] = v;
        }
        const int wave = tid8 >> 6;
        const int lane = tid8 & 63;
        __syncthreads();   // y consumed by ph5b; reuse s_yf as reduce buffer
        if (lane == 0) {
            #pragma unroll
            for (int c = 0; c < NCLS; ++c) s_yf[wave * NCLS + c] = p_[c];
        }
        __syncthreads();
        if (tid8 < NCLS) {
            float v = s_yf[tid8] + s_yf[NCLS + tid8] + s_yf[2 * NCLS + tid8] +
                      s_yf[3 * NCLS + tid8] + fc_b[tid8];
            out[(size_t)(b0 + p) * NCLS + tid8] = v;
        }
    }
}

extern "C" void kernel_launch(void* const* d_in, const int* in_sizes, int n_in,
                              void* d_out, int out_size, void* d_ws, size_t ws_size,
                              hipStream_t stream) {
    const float* x          = (const float*)d_in[0];
    const float* in_proj_w  = (const float*)d_in[1];
    const float* conv_w     = (const float*)d_in[2];
    const float* conv_b     = (const float*)d_in[3];
    const float* x_proj_w   = (const float*)d_in[4];
    const float* dt_proj_w  = (const float*)d_in[5];
    const float* dt_proj_b  = (const float*)d_in[6];
    const float* A_log      = (const float*)d_in[7];
    const float* Dp         = (const float*)d_in[8];
    const float* out_proj_w = (const float*)d_in[9];
    const float* fc_w       = (const float*)d_in[10];
    const float* fc_b       = (const float*)d_in[11];
    float* out = (float*)d_out;

    const int batch = in_sizes[0] / (8 * SEQ);  // 1024
    mamba_cls_kernel<<<batch / 2, 512, 0, stream>>>(
        x, in_proj_w, conv_w, conv_b, x_proj_w, dt_proj_w, dt_proj_b,
        A_log, Dp, out_proj_w, fc_w, fc_b, out);
}

// Round 11
// 61.144 us; speedup vs baseline: 1.3620x; 1.0357x over previous
//
#include <hip/hip_runtime.h>
#include <hip/hip_fp16.h>
#include <math.h>

#define SEQ 250
#define ST  252      // padded t-stride: rows 16B-aligned (ST*4 = 1008 = 63*16)
#define NCLS 12

// Butterfly add via DPP (zero DS-pipe ops).
// 0xB1=quad_perm xor1; 0x4E=quad_perm xor2; 0x141=row_half_mirror (lane^7,
// valid once quad-constant); 0x140=row_mirror (lane^15, once 8-group-constant).
template<int CTRL>
__device__ __forceinline__ float dpp_add(float v) {
    int t = __builtin_amdgcn_update_dpp(0, __float_as_int(v), CTRL, 0xF, 0xF, true);
    return v + __int_as_float(t);
}

__device__ __forceinline__ __half2 f_as_h2(float f) {
    union { float f; __half2 h; } u; u.f = f; return u.h;
}
__device__ __forceinline__ float h2_as_f(__half2 h) {
    union { __half2 h; float f; } u; u.h = h; return u.f;
}

// 512 threads, TWO batch elements per block.
// LDS: 2 x (s_bc 16128 + s_dlu 16128 + s_sz 8064) = 80,640 B -> 2 blocks/CU.
// r4-r6: no register live ranges across the scan (spills -> 45 MB scratch).
// r10 lesson: DS pipe is co-bottleneck -> all hot phases use b128/b64 LDS ops.
__global__ __launch_bounds__(512)
void mamba_cls_kernel(
    const float* __restrict__ x,         // (B, 8, 250)
    const float* __restrict__ in_proj_w, // (32, 8)
    const float* __restrict__ conv_w,    // (16, 4)
    const float* __restrict__ conv_b,    // (16)
    const float* __restrict__ x_proj_w,  // (33, 16)
    const float* __restrict__ dt_proj_w, // (16, 1)
    const float* __restrict__ dt_proj_b, // (16)
    const float* __restrict__ A_log,     // (16, 16)
    const float* __restrict__ Dp,        // (16)
    const float* __restrict__ out_proj_w,// (8, 16)
    const float* __restrict__ fc_w,      // (12, 2000)
    const float* __restrict__ fc_b,      // (12)
    float* __restrict__ out)             // (B, 12)
{
    // Per problem p:
    // s_bc [p]: ph1-2 x_in (f32 view [d*ST+t]); ph3+ {B,C} half2 [s*ST+t];
    //           ph5b+ out2000 (f32 view [t*8+j])
    // s_dlu   : ph0-1 staged x of BOTH problems (flat f32 from s_dlu[0]);
    //           ph2+ {dl,u} half2 [d*ST+t] (u=.y ph2, dl=.x ph3);
    //           ph4+ y (f32, same word); ph6 reduce partials
    // s_sz [p]: silu(z) fp16 [d*ST+t]
    __shared__ __align__(16) __half2 s_bc [2][16 * ST];
    __shared__ __align__(16) __half2 s_dlu[2][16 * ST];
    __shared__ __align__(16) __half  s_sz [2][16 * ST];

    const int tid  = threadIdx.x;
    const int p    = tid >> 8;
    const int tid8 = tid & 255;
    const int b0   = blockIdx.x * 2;

    // ---- Phase 0: stage x for BOTH problems coalesced (flat, stride 250)
    {
        float* s_xf = (float*)s_dlu[0];
        const float* __restrict__ xb = x + (size_t)b0 * (8 * SEQ);
        for (int i = tid; i < 2 * 8 * SEQ; i += 512) s_xf[i] = xb[i];
    }
    __syncthreads();

    // ---- Phase 1: x_in[d*ST+t] -> s_bc(f32) ; silu(z) -> s_sz
    {
        float* s_f  = (float*)s_bc[p];
        const float* s_xf = (const float*)s_dlu[0] + p * (8 * SEQ);
        const int d  = tid8 & 15;
        const int t0 = tid8 >> 4;
        float w1[8], w2[8];
        #pragma unroll
        for (int m = 0; m < 8; ++m) {
            w1[m] = in_proj_w[d * 8 + m];
            w2[m] = in_proj_w[(16 + d) * 8 + m];
        }
        #pragma unroll
        for (int i = 0; i < 16; ++i) {
            int t = t0 + i * 16;
            if (t < SEQ) {
                float acc = 0.f, z = 0.f;
                #pragma unroll
                for (int m = 0; m < 8; ++m) {
                    float xv = s_xf[m * SEQ + t];
                    acc = fmaf(w1[m], xv, acc);
                    z   = fmaf(w2[m], xv, z);
                }
                s_f[d * ST + t] = acc;
                s_sz[p][d * ST + t] = __float2half(z / (1.f + __expf(-z)));
            }
        }
    }
    __syncthreads();

    // ---- Phase 2: causal conv(k=4)+SiLU -> u into s_dlu[p][d*ST+t].y
    {
        const float* s_f = (const float*)s_bc[p];
        const int d  = tid8 & 15;
        const int t0 = tid8 >> 4;
        float cw[4];
        #pragma unroll
        for (int k = 0; k < 4; ++k) cw[k] = conv_w[d * 4 + k];
        const float cb = conv_b[d];
        #pragma unroll
        for (int i = 0; i < 16; ++i) {
            int t = t0 + i * 16;
            if (t < SEQ) {
                float acc = cb;
                #pragma unroll
                for (int k = 0; k < 4; ++k) {
                    int tt = t + k - 3;
                    if (tt >= 0) acc = fmaf(cw[k], s_f[d * ST + tt], acc);
                }
                float sg = 1.f / (1.f + __expf(-acc));
                s_dlu[p][d * ST + t].y = __float2half(acc * sg);
            }
        }
    }
    __syncthreads();

    // ---- Phase 3: {B,C} -> s_bc[p][s*ST+t..] ; dl -> s_dlu[p][s*ST+t].x
    // Mapping: s = tid8&15, 4t-chunk = tid8>>4; u read as 16 b128 row-segments
    // (broadcast across the 16 s-lanes), u = high half of each {dl,u} word.
    {
        const int s = tid8 & 15;
        __half2 wb2[8], wc2[8], wd2[8];
        #pragma unroll
        for (int k = 0; k < 8; ++k) {
            wb2[k] = __floats2half2_rn(x_proj_w[(1 + s) * 16 + 2 * k],
                                       x_proj_w[(1 + s) * 16 + 2 * k + 1]);
            wc2[k] = __floats2half2_rn(x_proj_w[(17 + s) * 16 + 2 * k],
                                       x_proj_w[(17 + s) * 16 + 2 * k + 1]);
            wd2[k] = __floats2half2_rn(x_proj_w[2 * k], x_proj_w[2 * k + 1]);
        }
        const float dws = dt_proj_w[s];
        const float dbs = dt_proj_b[s];
        const __half2 zero2 = __float2half2_rn(0.f);
        for (int t0 = (tid8 >> 4) * 4; t0 < SEQ; t0 += 64) {
            __half2 ab[4], ac[4], ad[4];
            #pragma unroll
            for (int tt = 0; tt < 4; ++tt) { ab[tt] = zero2; ac[tt] = zero2; ad[tt] = zero2; }
            #pragma unroll
            for (int k = 0; k < 8; ++k) {
                float4 qa = *reinterpret_cast<const float4*>(s_dlu[p] + (2 * k) * ST + t0);
                float4 qb = *reinterpret_cast<const float4*>(s_dlu[p] + (2 * k + 1) * ST + t0);
                float fa[4] = {qa.x, qa.y, qa.z, qa.w};
                float fb[4] = {qb.x, qb.y, qb.z, qb.w};
                #pragma unroll
                for (int tt = 0; tt < 4; ++tt) {
                    __half2 uv = __halves2half2(__high2half(f_as_h2(fa[tt])),
                                                __high2half(f_as_h2(fb[tt])));
                    ab[tt] = __hfma2(uv, wb2[k], ab[tt]);
                    ac[tt] = __hfma2(uv, wc2[k], ac[tt]);
                    ad[tt] = __hfma2(uv, wd2[k], ad[tt]);
                }
            }
            const bool full4 = (t0 + 3 < SEQ);
            __half2 bcv[4];
            #pragma unroll
            for (int tt = 0; tt < 4; ++tt) {
                if (full4 || t0 + tt < SEQ) {
                    float abf = __half2float(__low2half(ab[tt])) + __half2float(__high2half(ab[tt]));
                    float acf = __half2float(__low2half(ac[tt])) + __half2float(__high2half(ac[tt]));
                    float adf = __half2float(__low2half(ad[tt])) + __half2float(__high2half(ad[tt]));
                    bcv[tt] = __floats2half2_rn(abf, acf);
                    float v  = fmaf(adf, dws, dbs);
                    float dl = (v > 20.f) ? v : __logf(1.f + __expf(v));
                    s_dlu[p][s * ST + t0 + tt].x = __float2half(dl);
                }
            }
            if (full4) {
                float4 w4;
                w4.x = h2_as_f(bcv[0]); w4.y = h2_as_f(bcv[1]);
                w4.z = h2_as_f(bcv[2]); w4.w = h2_as_f(bcv[3]);
                *reinterpret_cast<float4*>(s_bc[p] + s * ST + t0) = w4;
            } else {
                #pragma unroll
                for (int tt = 0; tt < 4; ++tt)
                    if (t0 + tt < SEQ) s_bc[p][s * ST + t0 + tt] = bcv[tt];
            }
        }
    }
    __syncthreads();

    // ---- Phase 4: scan, s-folded x2, b128 per 4 timesteps (1 DS-op/t/wave).
    // Active: tid<256. waves 0-1 -> problem 0, waves 2-3 -> problem 1.
    // d = (tid&127)>>3, s2 = tid&7; states s2 and s2+8.
    if (tid < 256) {
        const int sp   = tid >> 7;
        const int i7   = tid & 127;
        const int d    = i7 >> 3;
        const int s2   = i7 & 7;
        const float A2a = -__expf(A_log[d * 16 + s2])     * 1.4426950408889634f;
        const float A2b = -__expf(A_log[d * 16 + s2 + 8]) * 1.4426950408889634f;
        const float Dd  = Dp[d];
        const __half2* __restrict__ dlu_p = s_dlu[sp] + d * ST;
        const __half2* __restrict__ bca_p = s_bc [sp] + s2 * ST;
        const __half2* __restrict__ bcb_p = s_bc [sp] + (s2 + 8) * ST;
        const __half*  __restrict__ sz_p  = (const __half*)s_sz[sp] + d * ST;
        float* __restrict__ y_p = (float*)s_dlu[sp] + d * ST;
        float ha = 0.f, hb = 0.f;
        for (int t = 0; t < 248; t += 4) {
            float4 duv4 = *reinterpret_cast<const float4*>(dlu_p + t);
            float4 bca4 = *reinterpret_cast<const float4*>(bca_p + t);
            float4 bcb4 = *reinterpret_cast<const float4*>(bcb_p + t);
            float2 sz2  = *reinterpret_cast<const float2*>(sz_p + t);
            float fdu[4] = {duv4.x, duv4.y, duv4.z, duv4.w};
            float fba[4] = {bca4.x, bca4.y, bca4.z, bca4.w};
            float fbb[4] = {bcb4.x, bcb4.y, bcb4.z, bcb4.w};
            float2 szl = __half22float2(f_as_h2(sz2.x));
            float2 szh = __half22float2(f_as_h2(sz2.y));
            float fsz[4] = {szl.x, szl.y, szh.x, szh.y};
            #pragma unroll
            for (int tt = 0; tt < 4; ++tt) {
                float2 du  = __half22float2(f_as_h2(fdu[tt]));
                float2 bca = __half22float2(f_as_h2(fba[tt]));
                float2 bcb = __half22float2(f_as_h2(fbb[tt]));
                float dlu = du.x * du.y;
                ha = fmaf(exp2f(du.x * A2a), ha, dlu * bca.x);
                hb = fmaf(exp2f(du.x * A2b), hb, dlu * bcb.x);
                float r = fmaf(hb, bcb.y, ha * bca.y);
                r = dpp_add<0xB1>(r);
                r = dpp_add<0x4E>(r);
                r = dpp_add<0x141>(r);
                if (s2 == 0) y_p[t + tt] = fmaf(du.y, Dd, r) * fsz[tt];
            }
        }
        {   // tail t = 248, 249
            float2 duv2 = *reinterpret_cast<const float2*>(dlu_p + 248);
            float2 bca2 = *reinterpret_cast<const float2*>(bca_p + 248);
            float2 bcb2 = *reinterpret_cast<const float2*>(bcb_p + 248);
            float2 szf  = __half22float2(*reinterpret_cast<const __half2*>(sz_p + 248));
            float fdu[2] = {duv2.x, duv2.y};
            float fba[2] = {bca2.x, bca2.y};
            float fbb[2] = {bcb2.x, bcb2.y};
            float fsz[2] = {szf.x, szf.y};
            #pragma unroll
            for (int tt = 0; tt < 2; ++tt) {
                float2 du  = __half22float2(f_as_h2(fdu[tt]));
                float2 bca = __half22float2(f_as_h2(fba[tt]));
                float2 bcb = __half22float2(f_as_h2(fbb[tt]));
                float dlu = du.x * du.y;
                ha = fmaf(exp2f(du.x * A2a), ha, dlu * bca.x);
                hb = fmaf(exp2f(du.x * A2b), hb, dlu * bcb.x);
                float r = fmaf(hb, bcb.y, ha * bca.y);
                r = dpp_add<0xB1>(r);
                r = dpp_add<0x4E>(r);
                r = dpp_add<0x141>(r);
                if (s2 == 0) y_p[248 + tt] = fmaf(du.y, Dd, r) * fsz[tt];
            }
        }
    }
    __syncthreads();

    // ---- Phase 5b: out2000[t*8+j] = sum_d y[d,t]*out_proj_w[j,d]
    // Mapping: j = tid8&7, 4t-chunk = tid8>>3; y read as b128 per d-row.
    {
        float* s_f  = (float*)s_bc[p];
        const float* s_yf = (const float*)s_dlu[p];
        const int j = tid8 & 7;
        float w[16];
        #pragma unroll
        for (int d2 = 0; d2 < 16; ++d2) w[d2] = out_proj_w[j * 16 + d2];
        for (int t0 = (tid8 >> 3) * 4; t0 < SEQ; t0 += 128) {
            float a0 = 0.f, a1 = 0.f, a2 = 0.f, a3 = 0.f;
            #pragma unroll
            for (int d2 = 0; d2 < 16; ++d2) {
                float4 y4 = *reinterpret_cast<const float4*>(s_yf + d2 * ST + t0);
                a0 = fmaf(w[d2], y4.x, a0);
                a1 = fmaf(w[d2], y4.y, a1);
                a2 = fmaf(w[d2], y4.z, a2);
                a3 = fmaf(w[d2], y4.w, a3);
            }
            s_f[(t0 + 0) * 8 + j] = a0;
            s_f[(t0 + 1) * 8 + j] = a1;
            if (t0 + 2 < SEQ) s_f[(t0 + 2) * 8 + j] = a2;
            if (t0 + 3 < SEQ) s_f[(t0 + 3) * 8 + j] = a3;
        }
    }
    __syncthreads();

    // ---- Phase 6: logits[c] = out2000 . fc_w[c,:] + fc_b[c]  (float4 loads)
    {
        float* s_yf = (float*)s_dlu[p];
        float p_[NCLS];
        #pragma unroll
        for (int c = 0; c < NCLS; ++c) p_[c] = 0.f;
        const float4* fw4 = (const float4*)fc_w;
        const float4* sf4 = (const float4*)s_bc[p];
        for (int q = tid8; q < 500; q += 256) {
            float4 f = sf4[q];
            #pragma unroll
            for (int c = 0; c < NCLS; ++c) {
                float4 wv = fw4[c * 500 + q];
                p_[c] += f.x * wv.x + f.y * wv.y + f.z * wv.z + f.w * wv.w;
            }
        }
        #pragma unroll
        for (int c = 0; c < NCLS; ++c) {
            float v = p_[c];
            v = dpp_add<0xB1>(v);
            v = dpp_add<0x4E>(v);
            v = dpp_add<0x141>(v);
            v = dpp_add<0x140>(v);
            v += __shfl_xor(v, 16);
            v += __shfl_xor(v, 32);
            p_[c] = v;
        }
        const int wave = tid8 >> 6;
        const int lane = tid8 & 63;
        __syncthreads();
        if (lane == 0) {
            #pragma unroll
            for (int c = 0; c < NCLS; ++c) s_yf[wave * NCLS + c] = p_[c];
        }
        __syncthreads();
        if (tid8 < NCLS) {
            float v = s_yf[tid8] + s_yf[NCLS + tid8] + s_yf[2 * NCLS + tid8] +
                      s_yf[3 * NCLS + tid8] + fc_b[tid8];
            out[(size_t)(b0 + p) * NCLS + tid8] = v;
        }
    }
}

extern "C" void kernel_launch(void* const* d_in, const int* in_sizes, int n_in,
                              void* d_out, int out_size, void* d_ws, size_t ws_size,
                              hipStream_t stream) {
    const float* x          = (const float*)d_in[0];
    const float* in_proj_w  = (const float*)d_in[1];
    const float* conv_w     = (const float*)d_in[2];
    const float* conv_b     = (const float*)d_in[3];
    const float* x_proj_w   = (const float*)d_in[4];
    const float* dt_proj_w  = (const float*)d_in[5];
    const float* dt_proj_b  = (const float*)d_in[6];
    const float* A_log      = (const float*)d_in[7];
    const float* Dp         = (const float*)d_in[8];
    const float* out_proj_w = (const float*)d_in[9];
    const float* fc_w       = (const float*)d_in[10];
    const float* fc_b       = (const float*)d_in[11];
    float* out = (float*)d_out;

    const int batch = in_sizes[0] / (8 * SEQ);  // 1024
    mamba_cls_kernel<<<batch / 2, 512, 0, stream>>>(
        x, in_proj_w, conv_w, conv_b, x_proj_w, dt_proj_w, dt_proj_b,
        A_log, Dp, out_proj_w, fc_w, fc_b, out);
}

// Round 12
// 54.841 us; speedup vs baseline: 1.5186x; 1.1149x over previous
//
#include <hip/hip_runtime.h>
#include <hip/hip_fp16.h>
#include <math.h>

#define SEQ 250
#define ST  252      // padded t-stride: rows 16B-aligned (ST*4 = 1008 = 63*16)
#define NCLS 12

typedef __attribute__((ext_vector_type(4))) _Float16 half4v;
typedef __attribute__((ext_vector_type(4))) float    float4v;

// Butterfly add via DPP (zero DS-pipe ops).
// 0xB1=quad_perm xor1; 0x4E=quad_perm xor2; 0x141=row_half_mirror (lane^7,
// valid once quad-constant); 0x140=row_mirror (lane^15, once 8-group-constant).
template<int CTRL>
__device__ __forceinline__ float dpp_add(float v) {
    int t = __builtin_amdgcn_update_dpp(0, __float_as_int(v), CTRL, 0xF, 0xF, true);
    return v + __int_as_float(t);
}

__device__ __forceinline__ __half2 f_as_h2(float f) {
    union { float f; __half2 h; } u; u.f = f; return u.h;
}
__device__ __forceinline__ float h2_as_f(__half2 h) {
    union { __half2 h; float f; } u; u.h = h; return u.f;
}

// 512 threads, TWO batch elements per block.
// LDS: 2 x (s_bc 16128 + s_dlu 16128 + s_sz 8064) = 80,640 B -> 2 blocks/CU.
// r4-r6: no register live ranges across the scan (spills -> 45 MB scratch).
// r11 lesson: issue-bound on total inst volume; MfmaUtil was 0 -> move the
// x_proj GEMM (phase 3) onto the idle matrix pipe via mfma_f32_16x16x16_f16.
__global__ __launch_bounds__(512)
void mamba_cls_kernel(
    const float* __restrict__ x,         // (B, 8, 250)
    const float* __restrict__ in_proj_w, // (32, 8)
    const float* __restrict__ conv_w,    // (16, 4)
    const float* __restrict__ conv_b,    // (16)
    const float* __restrict__ x_proj_w,  // (33, 16)
    const float* __restrict__ dt_proj_w, // (16, 1)
    const float* __restrict__ dt_proj_b, // (16)
    const float* __restrict__ A_log,     // (16, 16)
    const float* __restrict__ Dp,        // (16)
    const float* __restrict__ out_proj_w,// (8, 16)
    const float* __restrict__ fc_w,      // (12, 2000)
    const float* __restrict__ fc_b,      // (12)
    float* __restrict__ out)             // (B, 12)
{
    // Per problem p:
    // s_bc [p]: ph1-2 x_in (f32 view [d*ST+t]); ph3+ {B,C} half2 [s*ST+t];
    //           ph5b+ out2000 (f32 view [t*8+j])
    // s_dlu   : ph0-1 staged x of BOTH problems (flat f32 from s_dlu[0]);
    //           ph2+ {dl,u} half2 [d*ST+t] (u=.y ph2, dl=.x ph3);
    //           ph4+ y (f32, same word); ph6 reduce partials
    // s_sz [p]: silu(z) fp16 [d*ST+t]
    __shared__ __align__(16) __half2 s_bc [2][16 * ST];
    __shared__ __align__(16) __half2 s_dlu[2][16 * ST];
    __shared__ __align__(16) __half  s_sz [2][16 * ST];

    const int tid  = threadIdx.x;
    const int p    = tid >> 8;
    const int tid8 = tid & 255;
    const int b0   = blockIdx.x * 2;

    // ---- Phase 0: stage x for BOTH problems coalesced (flat, stride 250)
    {
        float* s_xf = (float*)s_dlu[0];
        const float* __restrict__ xb = x + (size_t)b0 * (8 * SEQ);
        for (int i = tid; i < 2 * 8 * SEQ; i += 512) s_xf[i] = xb[i];
    }
    __syncthreads();

    // ---- Phase 1: x_in[d*ST+t] -> s_bc(f32) ; silu(z) -> s_sz
    {
        float* s_f  = (float*)s_bc[p];
        const float* s_xf = (const float*)s_dlu[0] + p * (8 * SEQ);
        const int d  = tid8 & 15;
        const int t0 = tid8 >> 4;
        float w1[8], w2[8];
        #pragma unroll
        for (int m = 0; m < 8; ++m) {
            w1[m] = in_proj_w[d * 8 + m];
            w2[m] = in_proj_w[(16 + d) * 8 + m];
        }
        #pragma unroll
        for (int i = 0; i < 16; ++i) {
            int t = t0 + i * 16;
            if (t < SEQ) {
                float acc = 0.f, z = 0.f;
                #pragma unroll
                for (int m = 0; m < 8; ++m) {
                    float xv = s_xf[m * SEQ + t];
                    acc = fmaf(w1[m], xv, acc);
                    z   = fmaf(w2[m], xv, z);
                }
                s_f[d * ST + t] = acc;
                s_sz[p][d * ST + t] = __float2half(z / (1.f + __expf(-z)));
            }
        }
    }
    __syncthreads();

    // ---- Phase 2: causal conv(k=4)+SiLU -> u into s_dlu[p][d*ST+t].y
    {
        const float* s_f = (const float*)s_bc[p];
        const int d  = tid8 & 15;
        const int t0 = tid8 >> 4;
        float cw[4];
        #pragma unroll
        for (int k = 0; k < 4; ++k) cw[k] = conv_w[d * 4 + k];
        const float cb = conv_b[d];
        #pragma unroll
        for (int i = 0; i < 16; ++i) {
            int t = t0 + i * 16;
            if (t < SEQ) {
                float acc = cb;
                #pragma unroll
                for (int k = 0; k < 4; ++k) {
                    int tt = t + k - 3;
                    if (tt >= 0) acc = fmaf(cw[k], s_f[d * ST + tt], acc);
                }
                float sg = 1.f / (1.f + __expf(-acc));
                s_dlu[p][d * ST + t].y = __float2half(acc * sg);
            }
        }
    }
    __syncthreads();

    // ---- Phase 3 (MFMA): per 16-t tile, D = u(16t x 16d) * W(16d x 16col)
    // via v_mfma_f32_16x16x16_f16. A: lane(l&15 = t_local row, l>>4 = k-group)
    // holds u[t0+row][4kg..4kg+3] (gathered from {dl,u}.y, 4 x b32 + 2 perms).
    // B-tiles: W_B (B states), W_C (C states), W_dt (dt weights broadcast to
    // all 16 cols so every lane gets dt for its own 4 t's).
    // D: col = l&15 (= state s), row = (l>>4)*4 + reg (= t_local) -> 4
    // consecutive t per lane: {B,C} packed b128 write; dl 4 x b16 (predicated).
    {
        const int wave = tid8 >> 6;       // 0..3
        const int l    = tid8 & 63;
        const int rowc = l & 15;          // A-row (t_local) AND D-col (state)
        const int kg   = l >> 4;          // k-group

        half4v wB, wC, wD;
        #pragma unroll
        for (int i = 0; i < 4; ++i) {
            wB[i] = (_Float16)x_proj_w[(1  + rowc) * 16 + 4 * kg + i];
            wC[i] = (_Float16)x_proj_w[(17 + rowc) * 16 + 4 * kg + i];
            wD[i] = (_Float16)x_proj_w[4 * kg + i];
        }
        const float dtw_c = dt_proj_w[rowc];
        const float dtb_c = dt_proj_b[rowc];
        const float4v zero4 = {0.f, 0.f, 0.f, 0.f};
        const unsigned int* __restrict__ dlu_w = (const unsigned int*)s_dlu[p];

        for (int tile = wave; tile < 16; tile += 4) {
            const int t0 = tile * 16;
            // A-frag: u[t0+rowc][4kg+i] = high half of {dl,u} word
            unsigned int w0 = dlu_w[(4 * kg + 0) * ST + t0 + rowc];
            unsigned int w1 = dlu_w[(4 * kg + 1) * ST + t0 + rowc];
            unsigned int w2 = dlu_w[(4 * kg + 2) * ST + t0 + rowc];
            unsigned int w3 = dlu_w[(4 * kg + 3) * ST + t0 + rowc];
            union { unsigned int u[2]; half4v h; } A;
            A.u[0] = (w0 >> 16) | (w1 & 0xFFFF0000u);
            A.u[1] = (w2 >> 16) | (w3 & 0xFFFF0000u);

            float4v dB = __builtin_amdgcn_mfma_f32_16x16x16f16(A.h, wB, zero4, 0, 0, 0);
            float4v dC = __builtin_amdgcn_mfma_f32_16x16x16f16(A.h, wC, zero4, 0, 0, 0);
            float4v dT = __builtin_amdgcn_mfma_f32_16x16x16f16(A.h, wD, zero4, 0, 0, 0);

            const int tb = t0 + kg * 4;   // first of this lane's 4 t's
            if (tb <= 248) {              // words tb..tb+3 <= 251 (pad ok)
                __half2 h0 = __floats2half2_rn(dB[0], dC[0]);
                __half2 h1 = __floats2half2_rn(dB[1], dC[1]);
                __half2 h2 = __floats2half2_rn(dB[2], dC[2]);
                __half2 h3 = __floats2half2_rn(dB[3], dC[3]);
                float4 wv;
                wv.x = h2_as_f(h0); wv.y = h2_as_f(h1);
                wv.z = h2_as_f(h2); wv.w = h2_as_f(h3);
                *reinterpret_cast<float4*>(s_bc[p] + rowc * ST + tb) = wv;
            }
            #pragma unroll
            for (int r = 0; r < 4; ++r) {
                int t = tb + r;
                if (t < SEQ) {
                    float v  = fmaf(dT[r], dtw_c, dtb_c);
                    float dl = (v > 20.f) ? v : __logf(1.f + __expf(v));
                    s_dlu[p][rowc * ST + t].x = __float2half(dl);
                }
            }
        }
    }
    __syncthreads();

    // ---- Phase 4: scan, s-folded x2, b128 per 4 timesteps (1 DS-op/t/wave).
    // Active: tid<256. waves 0-1 -> problem 0, waves 2-3 -> problem 1.
    // d = (tid&127)>>3, s2 = tid&7; states s2 and s2+8.
    if (tid < 256) {
        const int sp   = tid >> 7;
        const int i7   = tid & 127;
        const int d    = i7 >> 3;
        const int s2   = i7 & 7;
        const float A2a = -__expf(A_log[d * 16 + s2])     * 1.4426950408889634f;
        const float A2b = -__expf(A_log[d * 16 + s2 + 8]) * 1.4426950408889634f;
        const float Dd  = Dp[d];
        const __half2* __restrict__ dlu_p = s_dlu[sp] + d * ST;
        const __half2* __restrict__ bca_p = s_bc [sp] + s2 * ST;
        const __half2* __restrict__ bcb_p = s_bc [sp] + (s2 + 8) * ST;
        const __half*  __restrict__ sz_p  = (const __half*)s_sz[sp] + d * ST;
        float* __restrict__ y_p = (float*)s_dlu[sp] + d * ST;
        float ha = 0.f, hb = 0.f;
        for (int t = 0; t < 248; t += 4) {
            float4 duv4 = *reinterpret_cast<const float4*>(dlu_p + t);
            float4 bca4 = *reinterpret_cast<const float4*>(bca_p + t);
            float4 bcb4 = *reinterpret_cast<const float4*>(bcb_p + t);
            float2 sz2  = *reinterpret_cast<const float2*>(sz_p + t);
            float fdu[4] = {duv4.x, duv4.y, duv4.z, duv4.w};
            float fba[4] = {bca4.x, bca4.y, bca4.z, bca4.w};
            float fbb[4] = {bcb4.x, bcb4.y, bcb4.z, bcb4.w};
            float2 szl = __half22float2(f_as_h2(sz2.x));
            float2 szh = __half22float2(f_as_h2(sz2.y));
            float fsz[4] = {szl.x, szl.y, szh.x, szh.y};
            #pragma unroll
            for (int tt = 0; tt < 4; ++tt) {
                float2 du  = __half22float2(f_as_h2(fdu[tt]));
                float2 bca = __half22float2(f_as_h2(fba[tt]));
                float2 bcb = __half22float2(f_as_h2(fbb[tt]));
                float dlu = du.x * du.y;
                ha = fmaf(exp2f(du.x * A2a), ha, dlu * bca.x);
                hb = fmaf(exp2f(du.x * A2b), hb, dlu * bcb.x);
                float r = fmaf(hb, bcb.y, ha * bca.y);
                r = dpp_add<0xB1>(r);
                r = dpp_add<0x4E>(r);
                r = dpp_add<0x141>(r);
                if (s2 == 0) y_p[t + tt] = fmaf(du.y, Dd, r) * fsz[tt];
            }
        }
        {   // tail t = 248, 249
            float2 duv2 = *reinterpret_cast<const float2*>(dlu_p + 248);
            float2 bca2 = *reinterpret_cast<const float2*>(bca_p + 248);
            float2 bcb2 = *reinterpret_cast<const float2*>(bcb_p + 248);
            float2 szf  = __half22float2(*reinterpret_cast<const __half2*>(sz_p + 248));
            float fdu[2] = {duv2.x, duv2.y};
            float fba[2] = {bca2.x, bca2.y};
            float fbb[2] = {bcb2.x, bcb2.y};
            float fsz[2] = {szf.x, szf.y};
            #pragma unroll
            for (int tt = 0; tt < 2; ++tt) {
                float2 du  = __half22float2(f_as_h2(fdu[tt]));
                float2 bca = __half22float2(f_as_h2(fba[tt]));
                float2 bcb = __half22float2(f_as_h2(fbb[tt]));
                float dlu = du.x * du.y;
                ha = fmaf(exp2f(du.x * A2a), ha, dlu * bca.x);
                hb = fmaf(exp2f(du.x * A2b), hb, dlu * bcb.x);
                float r = fmaf(hb, bcb.y, ha * bca.y);
                r = dpp_add<0xB1>(r);
                r = dpp_add<0x4E>(r);
                r = dpp_add<0x141>(r);
                if (s2 == 0) y_p[248 + tt] = fmaf(du.y, Dd, r) * fsz[tt];
            }
        }
    }
    __syncthreads();

    // ---- Phase 5b: out2000[t*8+j] = sum_d y[d,t]*out_proj_w[j,d]
    // Mapping: j = tid8&7, 4t-chunk = tid8>>3; y read as b128 per d-row.
    {
        float* s_f  = (float*)s_bc[p];
        const float* s_yf = (const float*)s_dlu[p];
        const int j = tid8 & 7;
        float w[16];
        #pragma unroll
        for (int d2 = 0; d2 < 16; ++d2) w[d2] = out_proj_w[j * 16 + d2];
        for (int t0 = (tid8 >> 3) * 4; t0 < SEQ; t0 += 128) {
            float a0 = 0.f, a1 = 0.f, a2 = 0.f, a3 = 0.f;
            #pragma unroll
            for (int d2 = 0; d2 < 16; ++d2) {
                float4 y4 = *reinterpret_cast<const float4*>(s_yf + d2 * ST + t0);
                a0 = fmaf(w[d2], y4.x, a0);
                a1 = fmaf(w[d2], y4.y, a1);
                a2 = fmaf(w[d2], y4.z, a2);
                a3 = fmaf(w[d2], y4.w, a3);
            }
            s_f[(t0 + 0) * 8 + j] = a0;
            s_f[(t0 + 1) * 8 + j] = a1;
            if (t0 + 2 < SEQ) s_f[(t0 + 2) * 8 + j] = a2;
            if (t0 + 3 < SEQ) s_f[(t0 + 3) * 8 + j] = a3;
        }
    }
    __syncthreads();

    // ---- Phase 6: logits[c] = out2000 . fc_w[c,:] + fc_b[c]  (float4 loads)
    {
        float* s_yf = (float*)s_dlu[p];
        float p_[NCLS];
        #pragma unroll
        for (int c = 0; c < NCLS; ++c) p_[c] = 0.f;
        const float4* fw4 = (const float4*)fc_w;
        const float4* sf4 = (const float4*)s_bc[p];
        for (int q = tid8; q < 500; q += 256) {
            float4 f = sf4[q];
            #pragma unroll
            for (int c = 0; c < NCLS; ++c) {
                float4 wv = fw4[c * 500 + q];
                p_[c] += f.x * wv.x + f.y * wv.y + f.z * wv.z + f.w * wv.w;
            }
        }
        #pragma unroll
        for (int c = 0; c < NCLS; ++c) {
            float v = p_[c];
            v = dpp_add<0xB1>(v);
            v = dpp_add<0x4E>(v);
            v = dpp_add<0x141>(v);
            v = dpp_add<0x140>(v);
            v += __shfl_xor(v, 16);
            v += __shfl_xor(v, 32);
            p_[c] = v;
        }
        const int wave = tid8 >> 6;
        const int lane = tid8 & 63;
        __syncthreads();
        if (lane == 0) {
            #pragma unroll
            for (int c = 0; c < NCLS; ++c) s_yf[wave * NCLS + c] = p_[c];
        }
        __syncthreads();
        if (tid8 < NCLS) {
            float v = s_yf[tid8] + s_yf[NCLS + tid8] + s_yf[2 * NCLS + tid8] +
                      s_yf[3 * NCLS + tid8] + fc_b[tid8];
            out[(size_t)(b0 + p) * NCLS + tid8] = v;
        }
    }
}

extern "C" void kernel_launch(void* const* d_in, const int* in_sizes, int n_in,
                              void* d_out, int out_size, void* d_ws, size_t ws_size,
                              hipStream_t stream) {
    const float* x          = (const float*)d_in[0];
    const float* in_proj_w  = (const float*)d_in[1];
    const float* conv_w     = (const float*)d_in[2];
    const float* conv_b     = (const float*)d_in[3];
    const float* x_proj_w   = (const float*)d_in[4];
    const float* dt_proj_w  = (const float*)d_in[5];
    const float* dt_proj_b  = (const float*)d_in[6];
    const float* A_log      = (const float*)d_in[7];
    const float* Dp         = (const float*)d_in[8];
    const float* out_proj_w = (const float*)d_in[9];
    const float* fc_w       = (const float*)d_in[10];
    const float* fc_b       = (const float*)d_in[11];
    float* out = (float*)d_out;

    const int batch = in_sizes[0] / (8 * SEQ);  // 1024
    mamba_cls_kernel<<<batch / 2, 512, 0, stream>>>(
        x, in_proj_w, conv_w, conv_b, x_proj_w, dt_proj_w, dt_proj_b,
        A_log, Dp, out_proj_w, fc_w, fc_b, out);
}